// Round 13
// baseline (86.488 us; speedup 1.0000x reference)
//
#include <hip/hip_runtime.h>

// SuperPointMatchesGenerator: B=8, N0=N1=2048 mutual-NN under homography.
// d_out f32, concat: gt_matches0[8,2048] | gt_matches1[8,2048] | min_dist0[8,2048]
//
// R13 vs R12 (84.9us; main ~27us vs 7.7us VALU floor; structural tweaks
// R9->R12 all neutral => main is ISSUE-RATE bound):
//  PACKED FP32: CDNA4 dual-FP32 (v_pk_mul/add/max_f32) doubles f32 issue
//  rate. Process 2 candidates per instruction for the 6 arith ops/pair;
//  selects stay scalar. 6 inst/pair vs 9. Requirements:
//   - SoA candidate layout (qx/qy/qs) so a candidate-pair is one aligned
//     8B v2f load per component (prep now writes SoA).
//   - #pragma clang fp contract(off) in the hot kernel: forbids pk_fma
//     fusion, keeping mul-then-add rounding bit-identical to numpy.
//   - pk ops are IEEE f32 round-to-nearest == scalar ops => d2 bit-exact.
//  Keep-first: thread processes pair-lo before pair-hi (sequential strict-<
//  selects), k ascending; cross-lane ties via u64 (d2bits<<32|idx) min.
//  Row-side x2 pre-double retained (exact; ab2 == 2*ab bitwise).
//
// LESSON (R11): no per-block __threadfence / fused finalize on CDNA4 —
// 3 clean dispatches (prep, main, final).
//
// FP exactness vs numpy-f32: p_i=(H0x+H1y)+H2; X=p0/(p2+1e-8); a2=X*X+Y*Y;
// d2=(a2+b2)-2ab; argmin on max(d2,0); winner e=sqrt(max(d2,0)); e>3.0 cut.
//
// ws (full path, 448KB): qx0|qy0|qs0|qx1|qy1|qs1 f32[16K] each | gt0p u16[16K]
// | gt1 u16[16K]. Fallback (ws < needed): R5-proven 64KB brute force.

#define SPN 2048
#define SPT 16384
#define RPB 16   // rows per block in main

typedef float v2f __attribute__((ext_vector_type(2)));

__device__ __forceinline__ void sp_reproject(const float* __restrict__ T, int b,
                                             float x, float y,
                                             float& X, float& Y, float& S) {
  const float* H = T + b * 9;
  float p0 = __fadd_rn(__fadd_rn(__fmul_rn(H[0], x), __fmul_rn(H[1], y)), H[2]);
  float p1 = __fadd_rn(__fadd_rn(__fmul_rn(H[3], x), __fmul_rn(H[4], y)), H[5]);
  float p2 = __fadd_rn(__fadd_rn(__fmul_rn(H[6], x), __fmul_rn(H[7], y)), H[8]);
  float den = __fadd_rn(p2, 1e-8f);
  X = __fdiv_rn(p0, den);
  Y = __fdiv_rn(p1, den);
  S = __fadd_rn(__fmul_rn(X, X), __fmul_rn(Y, Y));
}

__global__ __launch_bounds__(256) void sp_prep(
    const float2* __restrict__ k0, const float2* __restrict__ k1,
    const float* __restrict__ T,
    float* __restrict__ qx0, float* __restrict__ qy0, float* __restrict__ qs0,
    float* __restrict__ qx1, float* __restrict__ qy1, float* __restrict__ qs1) {
  int t = blockIdx.x * 256 + threadIdx.x;
  if (t < SPT) {
    float2 p = k0[t];
    float X, Y, S;
    sp_reproject(T, t >> 11, p.x, p.y, X, Y, S);
    qx0[t] = X; qy0[t] = Y; qs0[t] = S;
  } else {
    int u = t - SPT;
    float2 p = k1[u];
    qx1[u] = p.x; qy1[u] = p.y;
    qs1[u] = __fadd_rn(__fmul_rn(p.x, p.x), __fmul_rn(p.y, p.y));
  }
}

__global__ __launch_bounds__(256, 4) void SuperPointMatchesGenerator_56925496541369_kernel(
    const float* __restrict__ qx0, const float* __restrict__ qy0,
    const float* __restrict__ qs0, const float* __restrict__ qx1,
    const float* __restrict__ qy1, const float* __restrict__ qs1,
    unsigned short* __restrict__ gt0p, unsigned short* __restrict__ gt1,
    float* __restrict__ out_mind) {
#pragma clang fp contract(off)
  const bool m1 = blockIdx.x >= (SPT / RPB);      // block-uniform
  const int base = (m1 ? blockIdx.x - SPT / RPB : blockIdx.x) * RPB;
  const int b = base >> 11, cb = b << 11;
  const float* __restrict__ rxa = m1 ? qx1 : qx0;       // row arrays
  const float* __restrict__ rya = m1 ? qy1 : qy0;
  const float* __restrict__ rsa = m1 ? qs1 : qs0;
  const float* __restrict__ cxa = (m1 ? qx0 : qx1) + cb;  // candidate arrays
  const float* __restrict__ cya = (m1 ? qy0 : qy1) + cb;
  const float* __restrict__ csa = (m1 ? qs0 : qs1) + cb;

  float rx2[RPB], ry2[RPB], rs[RPB], bv[RPB];
  int bi[RPB];
#pragma unroll
  for (int r = 0; r < RPB; r++) {
    float x = rxa[base + r], y = rya[base + r];   // wave-uniform -> SGPRs
    rx2[r] = __fadd_rn(x, x);                     // exact doubling (row side only)
    ry2[r] = __fadd_rn(y, y);
    rs[r] = rsa[base + r];
    bv[r] = INFINITY; bi[r] = 0;
  }

  const v2f vzero = {0.0f, 0.0f};
  // thread covers candidate pairs {2t,2t+1}, {512+2t, ...}, ascending.
#pragma unroll
  for (int k = 0; k < 4; k++) {
    const int c = 2 * (int)threadIdx.x + 512 * k;
    v2f cx = *(const v2f*)(cxa + c);
    v2f cy = *(const v2f*)(cya + c);
    v2f cs = *(const v2f*)(csa + c);
#pragma unroll
    for (int r = 0; r < RPB; r++) {
      v2f t1 = rx2[r] * cx;                       // pk_mul
      v2f t2 = ry2[r] * cy;                       // pk_mul
      v2f ab2 = t1 + t2;                          // pk_add (no fma: contract off)
      v2f ss = rs[r] + cs;                        // pk_add (scalar broadcast)
      v2f d2 = ss - ab2;                          // pk_sub
      v2f dm = __builtin_elementwise_max(d2, vzero);  // pk_max
      // sequential lo-then-hi preserves keep-first within the pair
      if (dm.x < bv[r]) { bv[r] = dm.x; bi[r] = c; }
      if (dm.y < bv[r]) { bv[r] = dm.y; bi[r] = c + 1; }
    }
  }

  unsigned long long key[RPB];
#pragma unroll
  for (int r = 0; r < RPB; r++)
    key[r] = ((unsigned long long)__float_as_uint(bv[r]) << 32) | (unsigned)bi[r];
#pragma unroll
  for (int off = 32; off > 0; off >>= 1) {
#pragma unroll
    for (int r = 0; r < RPB; r++) {
      unsigned long long o = __shfl_down(key[r], off);
      if (o < key[r]) key[r] = o;
    }
  }
  __shared__ unsigned long long part[4][RPB];
  if ((threadIdx.x & 63) == 0) {
    int w = threadIdx.x >> 6;
#pragma unroll
    for (int r = 0; r < RPB; r++) part[w][r] = key[r];
  }
  __syncthreads();                                 // single barrier
  if (threadIdx.x < RPB) {
    int r = threadIdx.x;
    unsigned long long k = part[0][r];
#pragma unroll
    for (int w = 1; w < 4; w++)
      if (part[w][r] < k) k = part[w][r];
    int idx = (int)(k & 0x7ffu);
    if (!m1) {
      float e = __fsqrt_rn(__uint_as_float((unsigned)(k >> 32)));
      unsigned short pk = (unsigned short)idx;
      if (e > 3.0f) pk |= 0x8000u;                 // strict >, exact fp32
      gt0p[base + r] = pk;
      out_mind[base + r] = e;                      // min_dist0
    } else {
      gt1[base + r] = (unsigned short)idx;
    }
  }
}

__global__ __launch_bounds__(256) void SuperPointMatchesGenerator_56925496541369_final(
    const unsigned short* __restrict__ gt0p, const unsigned short* __restrict__ gt1,
    float* __restrict__ out) {
  int t = blockIdx.x * 256 + threadIdx.x;
  if (t >= SPT) return;
  int b = t >> 11, i = t & 2047, cb = b << 11;

  unsigned short p0 = gt0p[t];
  int m0 = p0 & 0x7ff;
  bool ok0 = ((p0 & 0x8000u) == 0) && ((int)gt1[cb + m0] == i);
  out[t] = ok0 ? (float)m0 : -1.0f;

  int istar = gt1[t];                              // gather form of the scatter
  unsigned short ps = gt0p[cb + istar];
  bool ok1 = (((int)(ps & 0x7ff)) == i) && ((ps & 0x8000u) == 0);
  out[SPT + t] = ok1 ? (float)istar : -1.0f;
}

// ---------- fallback (R5-proven, 64KB ws, 2 dispatches) ----------
__global__ __launch_bounds__(256) void sp_fb_main(
    const float2* __restrict__ k0, const float2* __restrict__ k1,
    const float* __restrict__ T, unsigned short* __restrict__ gt0p,
    unsigned short* __restrict__ gt1, float* __restrict__ out_mind) {
  const bool mode1 = blockIdx.x >= SPN;
  const int base = (mode1 ? blockIdx.x - SPN : blockIdx.x) * 8;
  const int b = base >> 11, cb = b << 11;
  float rx[8], ry[8], rs[8], bv[8];
  int bi[8];
#pragma unroll
  for (int r = 0; r < 8; r++) { bv[r] = INFINITY; bi[r] = 0; }
  if (!mode1) {
#pragma unroll
    for (int r = 0; r < 8; r++) {
      float2 p = k0[base + r];
      sp_reproject(T, b, p.x, p.y, rx[r], ry[r], rs[r]);
    }
    for (int c = threadIdx.x; c < SPN; c += 256) {
      float2 p = k1[cb + c];
      float b2 = __fadd_rn(__fmul_rn(p.x, p.x), __fmul_rn(p.y, p.y));
#pragma unroll
      for (int r = 0; r < 8; r++) {
        float ab = __fadd_rn(__fmul_rn(rx[r], p.x), __fmul_rn(ry[r], p.y));
        float d2 = __fsub_rn(__fadd_rn(rs[r], b2), __fmul_rn(2.0f, ab));
        float dm = fmaxf(d2, 0.0f);
        if (dm < bv[r]) { bv[r] = dm; bi[r] = c; }
      }
    }
  } else {
#pragma unroll
    for (int r = 0; r < 8; r++) {
      float2 p = k1[base + r];
      rx[r] = p.x; ry[r] = p.y;
      rs[r] = __fadd_rn(__fmul_rn(p.x, p.x), __fmul_rn(p.y, p.y));
    }
    for (int c = threadIdx.x; c < SPN; c += 256) {
      float2 p = k0[cb + c];
      float cx, cy, a2;
      sp_reproject(T, b, p.x, p.y, cx, cy, a2);
#pragma unroll
      for (int r = 0; r < 8; r++) {
        float ab = __fadd_rn(__fmul_rn(rx[r], cx), __fmul_rn(ry[r], cy));
        float d2 = __fsub_rn(__fadd_rn(a2, rs[r]), __fmul_rn(2.0f, ab));
        float dm = fmaxf(d2, 0.0f);
        if (dm < bv[r]) { bv[r] = dm; bi[r] = c; }
      }
    }
  }
  unsigned long long key[8];
#pragma unroll
  for (int r = 0; r < 8; r++)
    key[r] = ((unsigned long long)__float_as_uint(bv[r]) << 32) | (unsigned)bi[r];
#pragma unroll
  for (int off = 32; off > 0; off >>= 1) {
#pragma unroll
    for (int r = 0; r < 8; r++) {
      unsigned long long o = __shfl_down(key[r], off);
      if (o < key[r]) key[r] = o;
    }
  }
  __shared__ unsigned long long part[4][8];
  if ((threadIdx.x & 63) == 0) {
    int w = threadIdx.x >> 6;
#pragma unroll
    for (int r = 0; r < 8; r++) part[w][r] = key[r];
  }
  __syncthreads();
  if (threadIdx.x < 8) {
    int r = threadIdx.x;
    unsigned long long k = part[0][r];
#pragma unroll
    for (int w = 1; w < 4; w++)
      if (part[w][r] < k) k = part[w][r];
    int idx = (int)(k & 0x7ffu);
    if (!mode1) {
      float e = __fsqrt_rn(__uint_as_float((unsigned)(k >> 32)));
      unsigned short pk = (unsigned short)idx;
      if (e > 3.0f) pk |= 0x8000u;
      gt0p[base + r] = pk;
      out_mind[base + r] = e;
    } else {
      gt1[base + r] = (unsigned short)idx;
    }
  }
}

extern "C" void kernel_launch(void* const* d_in, const int* in_sizes, int n_in,
                              void* d_out, int out_size, void* d_ws, size_t ws_size,
                              hipStream_t stream) {
  (void)in_sizes; (void)n_in; (void)out_size;
  const float2* k0 = (const float2*)d_in[0];
  const float2* k1 = (const float2*)d_in[1];
  const float* T   = (const float*)d_in[2];
  float* out = (float*)d_out;

  const size_t need = (size_t)6 * SPT * sizeof(float)
                    + (size_t)2 * SPT * sizeof(unsigned short);
  if (ws_size >= need) {
    float* qx0 = (float*)d_ws;                     // 6 x 64 KB SoA
    float* qy0 = qx0 + SPT;
    float* qs0 = qy0 + SPT;
    float* qx1 = qs0 + SPT;
    float* qy1 = qx1 + SPT;
    float* qs1 = qy1 + SPT;
    unsigned short* gt0p = (unsigned short*)(qs1 + SPT);  // 32 KB
    unsigned short* gt1  = gt0p + SPT;                    // 32 KB
    sp_prep<<<2 * SPT / 256, 256, 0, stream>>>(k0, k1, T, qx0, qy0, qs0, qx1, qy1, qs1);
    SuperPointMatchesGenerator_56925496541369_kernel<<<2 * (SPT / RPB), 256, 0, stream>>>(
        qx0, qy0, qs0, qx1, qy1, qs1, gt0p, gt1, out + 2 * SPT);
    SuperPointMatchesGenerator_56925496541369_final<<<SPT / 256, 256, 0, stream>>>(
        gt0p, gt1, out);
  } else {
    unsigned short* gt0p = (unsigned short*)d_ws;
    unsigned short* gt1  = gt0p + SPT;
    sp_fb_main<<<2 * SPN, 256, 0, stream>>>(k0, k1, T, gt0p, gt1, out + 2 * SPT);
    SuperPointMatchesGenerator_56925496541369_final<<<SPT / 256, 256, 0, stream>>>(
        gt0p, gt1, out);
  }
}